// Round 7
// baseline (5899.278 us; speedup 1.0000x reference)
//
#include <hip/hip_runtime.h>
#include <math.h>

#define DIM 128
#define E_NUM 100000
#define P_NUM 800000
#define G_NUM 1000
#define T_STEPS 8
#define R_UNITS 256

typedef __attribute__((ext_vector_type(8))) short bf16x8;   // 8 bf16 = 4 VGPRs
typedef __attribute__((ext_vector_type(4))) float f32x4;    // 16x16 MFMA acc

typedef unsigned short ushort_t;
typedef unsigned int   uint_t;

__device__ __forceinline__ float selu_f(float x) {
    const float alpha = 1.6732632423543772f;
    const float scale = 1.0507009873554805f;
    return x > 0.f ? scale * x : scale * alpha * expm1f(x);
}

__device__ __forceinline__ ushort_t f2bf(float x) {
    uint_t u = __float_as_uint(x);
    uint_t r = (u + 0x7fffu + ((u >> 16) & 1u)) >> 16;
    return (ushort_t)r;
}
__device__ __forceinline__ float bf2f(ushort_t h) {
    return __uint_as_float(((uint_t)h) << 16);
}

// ===========================================================================
// CSR build (once per launch; states_second fixed across steps)
// ===========================================================================
__global__ __launch_bounds__(256)
void hist_kernel(const int* __restrict__ second, int* __restrict__ counts)
{
    const int p = blockIdx.x * 256 + threadIdx.x;
    atomicAdd(&counts[second[p]], 1);
}

__global__ __launch_bounds__(1024)
void scan_kernel(const int* __restrict__ counts, int* __restrict__ offsets)
{
    __shared__ int buf[1024];
    __shared__ int carry_s;
    const int tid = threadIdx.x;
    if (tid == 0) carry_s = 0;
    __syncthreads();
    for (int base = 0; base < E_NUM; base += 1024) {
        const int i = base + tid;
        const int v = (i < E_NUM) ? counts[i] : 0;
        buf[tid] = v;
        __syncthreads();
        for (int off = 1; off < 1024; off <<= 1) {
            const int t = (tid >= off) ? buf[tid - off] : 0;
            __syncthreads();
            buf[tid] += t;
            __syncthreads();
        }
        const int carry = carry_s;
        if (i < E_NUM) offsets[i] = carry + buf[tid] - v;
        __syncthreads();
        if (tid == 0) carry_s += buf[1023];
        __syncthreads();
    }
    if (tid == 0) offsets[E_NUM] = P_NUM;
}

__global__ __launch_bounds__(256)
void fill_kernel(const int* __restrict__ first, const int* __restrict__ second,
                 const int* __restrict__ offsets, int* __restrict__ cursor,
                 int* __restrict__ sfirst, int* __restrict__ ssecond)
{
    const int p = blockIdx.x * 256 + threadIdx.x;
    const int d = second[p];
    const int pos = atomicAdd(&cursor[d], 1);
    const int idx = offsets[d] + pos;
    sfirst[idx] = first[p];
    ssecond[idx] = d;
}

// ===========================================================================
// One-time prep.
// cast_h: split-bf16 (hi+lo) of link_state.
// wt (msg weights Wmsg [256,128]), frag-packed for DIRECT GLOBAL reads:
//   wt[ks(8)][comp(2)][nt(8)][lane(64)][8 bf16]; B[k][n]:
//   n = nt*16 + (lane&15), k = ks*32 + (lane>>4)*8 + j.   (128 KB, L2-hot)
// wb (GRU weights K,U [128,384] each), same frag scheme over combined N=384:
//   wb[ks(4)][gemm(2)][comp(2)][nt(24)][lane(64)][8 bf16]  (384 KB, L2-hot)
// ===========================================================================
__global__ __launch_bounds__(256)
void cast_h_kernel(const float* __restrict__ src,
                   ushort_t* __restrict__ dhi, ushort_t* __restrict__ dlo)
{
    const int idx = blockIdx.x * 256 + threadIdx.x;
    const float x = src[idx];
    const ushort_t hi = f2bf(x);
    dhi[idx] = hi;
    dlo[idx] = f2bf(x - bf2f(hi));
}

__global__ __launch_bounds__(256)
void wt_build_kernel(const float* __restrict__ Wmsg, ushort_t* __restrict__ wt)
{
    const int idx  = blockIdx.x * 256 + threadIdx.x;   // 8192 frag-slots
    const int lane = idx & 63;
    const int nt   = (idx >> 6) & 7;
    const int comp = (idx >> 9) & 1;
    const int ks   = idx >> 10;                        // 0..7
    const int n    = nt * 16 + (lane & 15);
    const int kb   = ks * 32 + (lane >> 4) * 8;
#pragma unroll
    for (int j = 0; j < 8; j++) {
        const float w = Wmsg[(size_t)(kb + j) * DIM + n];
        const ushort_t hi = f2bf(w);
        wt[(size_t)idx * 8 + j] = comp ? f2bf(w - bf2f(hi)) : hi;
    }
}

__global__ __launch_bounds__(256)
void wb_build_kernel(const float* __restrict__ K, const float* __restrict__ U,
                     ushort_t* __restrict__ wb)
{
    const int idx  = blockIdx.x * 256 + threadIdx.x;   // 24576 frag-slots
    const int lane = idx & 63;
    int t = idx >> 6;                                  // 0..383
    const int nt   = t % 24;  t /= 24;
    const int comp = t & 1;   t >>= 1;
    const int gemm = t & 1;
    const int ks   = t >> 1;                           // 0..3
    const float* src = gemm ? U : K;
    const int n  = nt * 16 + (lane & 15);
    const int kb = ks * 32 + (lane >> 4) * 8;
#pragma unroll
    for (int j = 0; j < 8; j++) {
        const float w = src[(size_t)(kb + j) * 384 + n];
        const ushort_t hi = f2bf(w);
        wb[(size_t)idx * 8 + j] = comp ? f2bf(w - bf2f(hi)) : hi;
    }
}

// ===========================================================================
// bf16x3 MFMA message kernel, LDS-staged A.
// Block: 256 thr (4 waves), M=64 pairs, N=128, K=256.
// Phase 1: stage A (hi+lo) into LDS in MFMA-fragment order — 4096 16B slots,
//   16 independent scattered gathers per thread (batched by compiler),
//   stride-1 ds_write_b128. Gathers per block: 64 (vs 256 when each wave
//   re-gathered its own copy).
// Phase 2: K-loop. A-frags via stride-1 ds_read_b128 (conflict-free);
//   B direct from global wt with explicit 2-stage register prefetch.
// Epilogue: bias+selu -> Ms (aliases A region) -> segmented sum by dst.
// LDS 66 KB -> 2 blocks/CU; (256,2) so VGPRs are unconstrained (<=256).
// ===========================================================================
#define MT 64
#define MS_STRIDE 132

__global__ __launch_bounds__(256, 2)
void msg_mfma3_kernel(const ushort_t* __restrict__ hbh, const ushort_t* __restrict__ hbl,
                      const int* __restrict__ sfirst, const int* __restrict__ ssecond,
                      const ushort_t* __restrict__ wt,
                      const float* __restrict__ bmsg, float* __restrict__ agg)
{
    // A-frag region: [comp(2)][ks(8)][rt(4)][lane(64)][16B] = 65536 B.
    // Ms (64 x 132 f32 = 33792 B) aliases it after the K-loop.
    __shared__ __align__(16) char smem[65536];
    __shared__ int f_s[MT], s_s[MT];
    __shared__ int prevdst, nextdst;

    float* Ms = (float*)smem;

    const int tid  = threadIdx.x;
    const int lane = tid & 63;
    const int w    = tid >> 6;
    const int p0   = blockIdx.x * MT;

    if (tid < MT) {
        f_s[tid] = sfirst[p0 + tid];
        s_s[tid] = ssecond[p0 + tid];
    }
    if (tid == 64) prevdst = (p0 == 0) ? -1 : ssecond[p0 - 1];
    if (tid == 65) nextdst = (p0 + MT >= P_NUM) ? -1 : ssecond[p0 + MT];
    __syncthreads();

    // ---- phase 1: stage A into LDS in fragment order ----
    // slot s (0..4095): lane_s = s&63, chunk c = s>>6; c = comp*32 + ks*4 + rt.
    // frag element: row_l = rt*16 + (lane_s&15), kg = ks*32 + (lane_s>>4)*8.
    {
        uint4 vals[16];
#pragma unroll
        for (int i = 0; i < 16; i++) {
            const int slot = i * 256 + tid;
            const int ls   = slot & 63;
            const int c    = slot >> 6;
            const int rt   = c & 3;
            const int ks   = (c >> 2) & 7;
            const int comp = c >> 5;
            const int row_l = rt * 16 + (ls & 15);
            const int kg    = ks * 32 + (ls >> 4) * 8;
            const int src   = (kg < DIM) ? f_s[row_l] : s_s[row_l];
            const int off   = kg & (DIM - 1);
            const ushort_t* g = (comp ? hbl : hbh) + (size_t)src * DIM + off;
            vals[i] = *(const uint4*)g;
        }
#pragma unroll
        for (int i = 0; i < 16; i++) {
            const int slot = i * 256 + tid;
            *(uint4*)(smem + (size_t)slot * 16) = vals[i];
        }
    }
    __syncthreads();

    // ---- phase 2: K-loop ----
    f32x4 acc[4][2];
#pragma unroll
    for (int rt = 0; rt < 4; rt++)
#pragma unroll
        for (int ntl = 0; ntl < 2; ntl++) acc[rt][ntl] = {};

    const int nt0 = w * 2, nt1 = w * 2 + 1;
    bf16x8 Bbuf[2][4];   // [stage][{nt0 hi, nt0 lo, nt1 hi, nt1 lo}]

#define LOAD_B(ks_, st_)                                                              \
    do {                                                                              \
        Bbuf[st_][0] = *(const bf16x8*)(wt + (size_t)((((ks_)*2 + 0)*8 + nt0)*64 + lane) * 8); \
        Bbuf[st_][1] = *(const bf16x8*)(wt + (size_t)((((ks_)*2 + 1)*8 + nt0)*64 + lane) * 8); \
        Bbuf[st_][2] = *(const bf16x8*)(wt + (size_t)((((ks_)*2 + 0)*8 + nt1)*64 + lane) * 8); \
        Bbuf[st_][3] = *(const bf16x8*)(wt + (size_t)((((ks_)*2 + 1)*8 + nt1)*64 + lane) * 8); \
    } while (0)

    LOAD_B(0, 0);

#pragma unroll
    for (int ks = 0; ks < 8; ks++) {
        if (ks < 7) {
            const int nk = ks + 1;
            if (nk & 1) LOAD_B(nk, 1); else LOAD_B(nk, 0);
        }
        bf16x8 a_h[4], a_l[4];
#pragma unroll
        for (int rt = 0; rt < 4; rt++) {
            a_h[rt] = *(const bf16x8*)(smem + (size_t)(((0 * 8 + ks) * 4 + rt) * 64 + lane) * 16);
            a_l[rt] = *(const bf16x8*)(smem + (size_t)(((1 * 8 + ks) * 4 + rt) * 64 + lane) * 16);
        }
        const bf16x8* B = Bbuf[ks & 1];
#pragma unroll
        for (int rt = 0; rt < 4; rt++) {
            acc[rt][0] = __builtin_amdgcn_mfma_f32_16x16x32_bf16(a_h[rt], B[0], acc[rt][0], 0, 0, 0);
            acc[rt][0] = __builtin_amdgcn_mfma_f32_16x16x32_bf16(a_l[rt], B[0], acc[rt][0], 0, 0, 0);
            acc[rt][0] = __builtin_amdgcn_mfma_f32_16x16x32_bf16(a_h[rt], B[1], acc[rt][0], 0, 0, 0);
            acc[rt][1] = __builtin_amdgcn_mfma_f32_16x16x32_bf16(a_h[rt], B[2], acc[rt][1], 0, 0, 0);
            acc[rt][1] = __builtin_amdgcn_mfma_f32_16x16x32_bf16(a_l[rt], B[2], acc[rt][1], 0, 0, 0);
            acc[rt][1] = __builtin_amdgcn_mfma_f32_16x16x32_bf16(a_h[rt], B[3], acc[rt][1], 0, 0, 0);
        }
    }
#undef LOAD_B

    __syncthreads();   // done reading A region; safe to overwrite with Ms

    // ---- epilogue: bias + selu into Ms (C layout: col=lane&15, row=quad*4+reg) ----
    const int m16  = lane & 15;
    const int quad = lane >> 4;
#pragma unroll
    for (int ntl = 0; ntl < 2; ntl++) {
        const int c = (w * 2 + ntl) * 16 + m16;
        const float bb = bmsg[c];
#pragma unroll
        for (int rt = 0; rt < 4; rt++) {
#pragma unroll
            for (int reg = 0; reg < 4; reg++) {
                const int row = rt * 16 + quad * 4 + reg;
                Ms[row * MS_STRIDE + c] = selu_f(acc[rt][ntl][reg] + bb);
            }
        }
    }
    __syncthreads();

    // ---- segmented reduction by destination ----
    const int r  = tid & 63;
    const int cg = tid >> 6;
    const int d  = s_s[r];
    const bool leader = (r == 0) || (d != s_s[r - 1]);
    if (leader) {
        int end = r + 1;
        while (end < MT && s_s[end] == d) end++;
        const bool needs_atomic = (r == 0 && d == prevdst) ||
                                  (end == MT && d == nextdst);
        float sacc[32];
#pragma unroll
        for (int c = 0; c < 32; c++) sacc[c] = 0.f;
        for (int rr = r; rr < end; rr++) {
            const float* mrow = Ms + rr * MS_STRIDE + cg * 32;
#pragma unroll
            for (int c = 0; c < 32; c++) sacc[c] += mrow[c];
        }
        float* dst = agg + (size_t)d * DIM + cg * 32;
        if (needs_atomic) {
#pragma unroll
            for (int c = 0; c < 32; c++) atomicAdd(dst + c, sacc[c]);
        } else {
#pragma unroll
            for (int c4 = 0; c4 < 8; c4++) {
                float4 v = make_float4(sacc[c4 * 4], sacc[c4 * 4 + 1],
                                       sacc[c4 * 4 + 2], sacc[c4 * 4 + 3]);
                *(float4*)(dst + c4 * 4) = v;
            }
        }
    }
}

// ===========================================================================
// bf16x3 MFMA GRU kernel (unchanged from R6).
// ===========================================================================
#define EXS 132

__global__ __launch_bounds__(256, 2)
void gru_mfma_kernel(const float* __restrict__ agg,
                     ushort_t* __restrict__ hbh, ushort_t* __restrict__ hbl,
                     const ushort_t* __restrict__ wb,
                     const float* __restrict__ bias)
{
    __shared__ float ex[4 * 32 * EXS];            // 67584 B
    const int tid  = threadIdx.x;
    const int lane = tid & 63;
    const int w    = tid >> 6;
    const int e0   = blockIdx.x * 32;
    const int m16  = lane & 15;
    const int quad = lane >> 4;

    f32x4 ax[2][6], ah[2][6];
#pragma unroll
    for (int rt = 0; rt < 2; rt++)
#pragma unroll
        for (int n = 0; n < 6; n++) { ax[rt][n] = {}; ah[rt][n] = {}; }

#pragma unroll
    for (int ks = 0; ks < 4; ks++) {
        const int koff = ks * 32 + quad * 8;
        bf16x8 xh_[2], xl_[2], hh_[2], hl_[2];
#pragma unroll
        for (int rt = 0; rt < 2; rt++) {
            const size_t grow = (size_t)(e0 + rt * 16 + m16);
            const float* xp = agg + grow * DIM + koff;
            const float4 v0 = *(const float4*)xp;
            const float4 v1 = *(const float4*)(xp + 4);
            float xv[8] = {v0.x, v0.y, v0.z, v0.w, v1.x, v1.y, v1.z, v1.w};
            bf16x8 xh_t, xl_t;
#pragma unroll
            for (int j = 0; j < 8; j++) {
                const ushort_t hi = f2bf(xv[j]);
                xh_t[j] = (short)hi;
                xl_t[j] = (short)f2bf(xv[j] - bf2f(hi));
            }
            xh_[rt] = xh_t;
            xl_[rt] = xl_t;
            hh_[rt] = *(const bf16x8*)(hbh + grow * DIM + koff);
            hl_[rt] = *(const bf16x8*)(hbl + grow * DIM + koff);
        }
#pragma unroll
        for (int ntl = 0; ntl < 6; ntl++) {
            const int nt = w * 6 + ntl;
            const size_t base = (size_t)(ks * 2) * 2 * 24;   // [ks][gemm][comp]
            const bf16x8 bKh = *(const bf16x8*)(wb + (((base + 0 * 24) + nt) * 64 + lane) * 8);
            const bf16x8 bKl = *(const bf16x8*)(wb + (((base + 1 * 24) + nt) * 64 + lane) * 8);
            const bf16x8 bUh = *(const bf16x8*)(wb + (((base + 2 * 24) + nt) * 64 + lane) * 8);
            const bf16x8 bUl = *(const bf16x8*)(wb + (((base + 3 * 24) + nt) * 64 + lane) * 8);
#pragma unroll
            for (int rt = 0; rt < 2; rt++) {
                ax[rt][ntl] = __builtin_amdgcn_mfma_f32_16x16x32_bf16(xh_[rt], bKh, ax[rt][ntl], 0, 0, 0);
                ax[rt][ntl] = __builtin_amdgcn_mfma_f32_16x16x32_bf16(xl_[rt], bKh, ax[rt][ntl], 0, 0, 0);
                ax[rt][ntl] = __builtin_amdgcn_mfma_f32_16x16x32_bf16(xh_[rt], bKl, ax[rt][ntl], 0, 0, 0);
                ah[rt][ntl] = __builtin_amdgcn_mfma_f32_16x16x32_bf16(hh_[rt], bUh, ah[rt][ntl], 0, 0, 0);
                ah[rt][ntl] = __builtin_amdgcn_mfma_f32_16x16x32_bf16(hl_[rt], bUh, ah[rt][ntl], 0, 0, 0);
                ah[rt][ntl] = __builtin_amdgcn_mfma_f32_16x16x32_bf16(hh_[rt], bUl, ah[rt][ntl], 0, 0, 0);
            }
        }
    }

    // ---- exchange: planes 0=z-sum, 1=r-sum, 2=xh, 3=rh ----
#pragma unroll
    for (int ntl = 0; ntl < 6; ntl++) {
        const int cglob = (w * 6 + ntl) * 16 + m16;     // 0..383
        const int gb = cglob >> 7;                       // 0=z 1=r 2=h
        const int cb = cglob & 127;
        const float b0v = bias[cglob];
        const float b1v = bias[384 + cglob];
#pragma unroll
        for (int rt = 0; rt < 2; rt++) {
#pragma unroll
            for (int reg = 0; reg < 4; reg++) {
                const int row = rt * 16 + quad * 4 + reg;
                const float mx = ax[rt][ntl][reg] + b0v;
                const float mh = ah[rt][ntl][reg] + b1v;
                if (gb == 0)      ex[0 * 32 * EXS + row * EXS + cb] = mx + mh;
                else if (gb == 1) ex[1 * 32 * EXS + row * EXS + cb] = mx + mh;
                else {
                    ex[2 * 32 * EXS + row * EXS + cb] = mx;
                    ex[3 * 32 * EXS + row * EXS + cb] = mh;
                }
            }
        }
    }
    __syncthreads();

    // ---- gates: thread t -> row t>>3, cols (t&7)*16 .. +15 ----
    const int row = tid >> 3;
    const int c0  = (tid & 7) * 16;
    const size_t gbase = (size_t)(e0 + row) * DIM;
#pragma unroll
    for (int j = 0; j < 16; j++) {
        const int c = c0 + j;
        const float sz = ex[0 * 32 * EXS + row * EXS + c];
        const float sr = ex[1 * 32 * EXS + row * EXS + c];
        const float xh = ex[2 * 32 * EXS + row * EXS + c];
        const float rh = ex[3 * 32 * EXS + row * EXS + c];
        const float z  = 1.f / (1.f + expf(-sz));
        const float r  = 1.f / (1.f + expf(-sr));
        const float hc = tanhf(xh + r * rh);
        const size_t g = gbase + c;
        const float hp = bf2f(hbh[g]) + bf2f(hbl[g]);
        const float hn = z * hp + (1.f - z) * hc;
        const ushort_t hi = f2bf(hn);
        hbh[g] = hi;
        hbl[g] = f2bf(hn - bf2f(hi));
    }
}

// ===========================================================================
// Graph pooling + readout
// ===========================================================================
__global__ __launch_bounds__(256)
void pool_kernel(const ushort_t* __restrict__ hbh, const ushort_t* __restrict__ hbl,
                 const int* __restrict__ gid, float* __restrict__ pooled)
{
    const int idx = blockIdx.x * 256 + threadIdx.x;
    const int e = idx >> 7;
    const int n = idx & 127;
    const float hv = bf2f(hbh[idx]) + bf2f(hbl[idx]);
    atomicAdd(pooled + (size_t)gid[e] * DIM + n, hv);
}

__global__ __launch_bounds__(256)
void readout_kernel(const float* __restrict__ pooled,
                    const float* __restrict__ W1, const float* __restrict__ b1,
                    const float* __restrict__ W2, const float* __restrict__ b2,
                    const float* __restrict__ W3, const float* __restrict__ b3,
                    float* __restrict__ out)
{
    __shared__ float sp[DIM];
    __shared__ float s1[R_UNITS];
    __shared__ float s2[R_UNITS];
    const int g = blockIdx.x, tid = threadIdx.x;

    if (tid < DIM) sp[tid] = pooled[(size_t)g * DIM + tid];
    __syncthreads();

    float acc = b1[tid];
    for (int k = 0; k < DIM; k++) acc += sp[k] * W1[(size_t)k * R_UNITS + tid];
    s1[tid] = selu_f(acc);
    __syncthreads();

    acc = b2[tid];
    for (int k = 0; k < R_UNITS; k++) acc += s1[k] * W2[(size_t)k * R_UNITS + tid];
    s2[tid] = selu_f(acc) * W3[tid];
    __syncthreads();

    for (int s = 128; s > 0; s >>= 1) {
        if (tid < s) s2[tid] += s2[tid + s];
        __syncthreads();
    }
    if (tid == 0) out[g] = s2[0] + b3[0];
}

// ===========================================================================
extern "C" void kernel_launch(void* const* d_in, const int* in_sizes, int n_in,
                              void* d_out, int out_size, void* d_ws, size_t ws_size,
                              hipStream_t stream)
{
    const float* link_state = (const float*)d_in[0];
    const int*   gids       = (const int*)d_in[1];
    const int*   first      = (const int*)d_in[2];
    const int*   second     = (const int*)d_in[3];
    const float* Wmsg       = (const float*)d_in[5];
    const float* bmsg       = (const float*)d_in[6];
    const float* gK         = (const float*)d_in[7];
    const float* gU         = (const float*)d_in[8];
    const float* gbias      = (const float*)d_in[9];
    const float* W1         = (const float*)d_in[10];
    const float* b1         = (const float*)d_in[11];
    const float* W2         = (const float*)d_in[12];
    const float* b2         = (const float*)d_in[13];
    const float* W3         = (const float*)d_in[14];
    const float* b3         = (const float*)d_in[15];
    float* out = (float*)d_out;

    // ws layout (all segments 16B aligned):
    //   offsets[100004] counts[1e5] cursor[1e5] sfirst[P] ssecond[P]
    //   wt[65536 us] wb[196608 us] hb_hi[E*128 us] hb_lo[E*128 us] agg[E*128 f32]
    int* offsets = (int*)d_ws;
    int* counts  = offsets + 100004;
    int* cursor  = counts + E_NUM;
    int* sfirst  = cursor + E_NUM;
    int* ssecond = sfirst + P_NUM;
    ushort_t* wt    = (ushort_t*)(ssecond + P_NUM);
    ushort_t* wb    = wt + 65536;
    ushort_t* hb_hi = wb + 196608;
    ushort_t* hb_lo = hb_hi + (size_t)E_NUM * DIM;
    float*    agg   = (float*)(hb_lo + (size_t)E_NUM * DIM);

    const size_t agg_bytes = (size_t)E_NUM * DIM * sizeof(float);

    // ---- one-time prep ----
    hipMemsetAsync(counts, 0, E_NUM * sizeof(int), stream);
    hipMemsetAsync(cursor, 0, E_NUM * sizeof(int), stream);
    hist_kernel<<<P_NUM / 256, 256, 0, stream>>>(second, counts);
    scan_kernel<<<1, 1024, 0, stream>>>(counts, offsets);
    fill_kernel<<<P_NUM / 256, 256, 0, stream>>>(first, second, offsets, cursor,
                                                 sfirst, ssecond);
    wt_build_kernel<<<32, 256, 0, stream>>>(Wmsg, wt);
    wb_build_kernel<<<96, 256, 0, stream>>>(gK, gU, wb);
    cast_h_kernel<<<(E_NUM * DIM) / 256, 256, 0, stream>>>(link_state, hb_hi, hb_lo);

    // ---- message-passing steps ----
    for (int t = 0; t < T_STEPS; t++) {
        hipMemsetAsync(agg, 0, agg_bytes, stream);
        msg_mfma3_kernel<<<P_NUM / MT, 256, 0, stream>>>(hb_hi, hb_lo,
                                                         sfirst, ssecond,
                                                         wt, bmsg, agg);
        gru_mfma_kernel<<<E_NUM / 32, 256, 0, stream>>>(agg, hb_hi, hb_lo,
                                                        wb, gbias);
    }

    // ---- pool + readout ----
    float* pooled = agg;  // reuse
    hipMemsetAsync(pooled, 0, (size_t)G_NUM * DIM * sizeof(float), stream);
    pool_kernel<<<(E_NUM * DIM) / 256, 256, 0, stream>>>(hb_hi, hb_lo, gids, pooled);
    readout_kernel<<<G_NUM, 256, 0, stream>>>(pooled, W1, b1, W2, b2, W3, b3, out);
}

// Round 8
// 4903.263 us; speedup vs baseline: 1.2031x; 1.2031x over previous
//
#include <hip/hip_runtime.h>
#include <math.h>

#define DIM 128
#define E_NUM 100000
#define P_NUM 800000
#define G_NUM 1000
#define T_STEPS 8
#define R_UNITS 256

typedef __attribute__((ext_vector_type(8))) short bf16x8;   // 8 bf16 = 4 VGPRs
typedef __attribute__((ext_vector_type(4))) float f32x4;    // 16x16 MFMA acc

typedef unsigned short ushort_t;
typedef unsigned int   uint_t;

__device__ __forceinline__ float selu_f(float x) {
    const float alpha = 1.6732632423543772f;
    const float scale = 1.0507009873554805f;
    return x > 0.f ? scale * x : scale * alpha * expm1f(x);
}

__device__ __forceinline__ ushort_t f2bf(float x) {
    uint_t u = __float_as_uint(x);
    uint_t r = (u + 0x7fffu + ((u >> 16) & 1u)) >> 16;
    return (ushort_t)r;
}
__device__ __forceinline__ float bf2f(ushort_t h) {
    return __uint_as_float(((uint_t)h) << 16);
}

// ===========================================================================
// CSR build (once per launch). Multi-block scan (single-block scan was slow).
// ===========================================================================
__global__ __launch_bounds__(256)
void hist_kernel(const int* __restrict__ second, int* __restrict__ counts)
{
    const int p = blockIdx.x * 256 + threadIdx.x;
    atomicAdd(&counts[second[p]], 1);
}

__global__ __launch_bounds__(1024)
void scanA_kernel(const int* __restrict__ counts, int* __restrict__ offsets,
                  int* __restrict__ bsum)
{
    __shared__ int buf[1024];
    const int i = blockIdx.x * 1024 + threadIdx.x;
    const int v = (i < E_NUM) ? counts[i] : 0;
    buf[threadIdx.x] = v;
    __syncthreads();
    for (int off = 1; off < 1024; off <<= 1) {
        const int t = (threadIdx.x >= off) ? buf[threadIdx.x - off] : 0;
        __syncthreads();
        buf[threadIdx.x] += t;
        __syncthreads();
    }
    if (i < E_NUM) offsets[i] = buf[threadIdx.x] - v;   // block-local exclusive
    if (threadIdx.x == 1023) bsum[blockIdx.x] = buf[1023];
}

__global__ void scanB_kernel(int* __restrict__ bsum, int* __restrict__ offsets)
{
    int acc = 0;
    for (int b = 0; b < 98; b++) { const int t = bsum[b]; bsum[b] = acc; acc += t; }
    offsets[E_NUM] = P_NUM;
}

__global__ __launch_bounds__(1024)
void scanC_kernel(int* __restrict__ offsets, const int* __restrict__ bsum)
{
    const int i = blockIdx.x * 1024 + threadIdx.x;
    if (i < E_NUM) offsets[i] += bsum[blockIdx.x];
}

__global__ __launch_bounds__(256)
void fill_kernel(const int* __restrict__ first, const int* __restrict__ second,
                 const int* __restrict__ offsets, int* __restrict__ cursor,
                 int* __restrict__ sfirst, int* __restrict__ ssecond)
{
    const int p = blockIdx.x * 256 + threadIdx.x;
    const int d = second[p];
    const int pos = atomicAdd(&cursor[d], 1);
    const int idx = offsets[d] + pos;
    sfirst[idx] = first[p];
    ssecond[idx] = d;
}

// ===========================================================================
// One-time prep.
// cast_h: split-bf16 (hi+lo) of link_state.
// wsplit: Wmsg [256,128] split into W_top (k 0..127) -> wt, W_bot -> wy,
//   each frag-packed [ks(4)][comp(2)][nt(8)][lane(64)][8 bf16]:
//   B[k][n]: n = nt*16 + (lane&15), k = ks*32 + (lane>>4)*8 + j.
// wb (GRU weights K,U [128,384]): [ks(4)][gemm(2)][comp(2)][nt(24)][lane][8].
// ===========================================================================
__global__ __launch_bounds__(256)
void cast_h_kernel(const float* __restrict__ src,
                   ushort_t* __restrict__ dhi, ushort_t* __restrict__ dlo)
{
    const int idx = blockIdx.x * 256 + threadIdx.x;
    const float x = src[idx];
    const ushort_t hi = f2bf(x);
    dhi[idx] = hi;
    dlo[idx] = f2bf(x - bf2f(hi));
}

__global__ __launch_bounds__(256)
void wsplit_build_kernel(const float* __restrict__ Wmsg,
                         ushort_t* __restrict__ wt, ushort_t* __restrict__ wy)
{
    const int idx  = blockIdx.x * 256 + threadIdx.x;   // 8192 slots (2 halves)
    const int lane = idx & 63;
    const int nt   = (idx >> 6) & 7;
    const int comp = (idx >> 9) & 1;
    const int ks   = (idx >> 10) & 3;
    const int half = idx >> 12;
    const int n    = nt * 16 + (lane & 15);
    const int kb   = ks * 32 + (lane >> 4) * 8 + half * 128;
    ushort_t* dst  = half ? wy : wt;
    const int slot = idx & 4095;
#pragma unroll
    for (int j = 0; j < 8; j++) {
        const float w = Wmsg[(size_t)(kb + j) * DIM + n];
        const ushort_t hi = f2bf(w);
        dst[(size_t)slot * 8 + j] = comp ? f2bf(w - bf2f(hi)) : hi;
    }
}

__global__ __launch_bounds__(256)
void wb_build_kernel(const float* __restrict__ K, const float* __restrict__ U,
                     ushort_t* __restrict__ wb)
{
    const int idx  = blockIdx.x * 256 + threadIdx.x;   // 24576 slots
    const int lane = idx & 63;
    int t = idx >> 6;
    const int nt   = t % 24;  t /= 24;
    const int comp = t & 1;   t >>= 1;
    const int gemm = t & 1;
    const int ks   = t >> 1;
    const float* src = gemm ? U : K;
    const int n  = nt * 16 + (lane & 15);
    const int kb = ks * 32 + (lane >> 4) * 8;
#pragma unroll
    for (int j = 0; j < 8; j++) {
        const float w = src[(size_t)(kb + j) * 384 + n];
        const ushort_t hi = f2bf(w);
        wb[(size_t)idx * 8 + j] = comp ? f2bf(w - bf2f(hi)) : hi;
    }
}

// ===========================================================================
// Y2 kernel: Y2 = h @ W_bot  [E x 128], bf16x3 MFMA. Block 256 thr, M=32
// (3125 blocks exact). Wave w -> nt {2w, 2w+1}; A (contiguous rows) read by
// all waves (L1-shared).
// ===========================================================================
__global__ __launch_bounds__(256, 4)
void y2_kernel(const ushort_t* __restrict__ hbh, const ushort_t* __restrict__ hbl,
               const ushort_t* __restrict__ wy, float* __restrict__ Y2)
{
    const int tid  = threadIdx.x;
    const int lane = tid & 63;
    const int w    = tid >> 6;
    const int e0   = blockIdx.x * 32;
    const int m16  = lane & 15;
    const int quad = lane >> 4;

    f32x4 acc[2][2] = {};
#pragma unroll
    for (int ks = 0; ks < 4; ks++) {
        const int koff = ks * 32 + quad * 8;
        bf16x8 ah[2], al[2];
#pragma unroll
        for (int rt = 0; rt < 2; rt++) {
            const size_t row = (size_t)(e0 + rt * 16 + m16);
            ah[rt] = *(const bf16x8*)(hbh + row * DIM + koff);
            al[rt] = *(const bf16x8*)(hbl + row * DIM + koff);
        }
#pragma unroll
        for (int ntl = 0; ntl < 2; ntl++) {
            const int nt = w * 2 + ntl;
            const bf16x8 bh = *(const bf16x8*)(wy + (size_t)(((ks * 2 + 0) * 8 + nt) * 64 + lane) * 8);
            const bf16x8 bl = *(const bf16x8*)(wy + (size_t)(((ks * 2 + 1) * 8 + nt) * 64 + lane) * 8);
#pragma unroll
            for (int rt = 0; rt < 2; rt++) {
                acc[rt][ntl] = __builtin_amdgcn_mfma_f32_16x16x32_bf16(ah[rt], bh, acc[rt][ntl], 0, 0, 0);
                acc[rt][ntl] = __builtin_amdgcn_mfma_f32_16x16x32_bf16(al[rt], bh, acc[rt][ntl], 0, 0, 0);
                acc[rt][ntl] = __builtin_amdgcn_mfma_f32_16x16x32_bf16(ah[rt], bl, acc[rt][ntl], 0, 0, 0);
            }
        }
    }
    // C layout: col = lane&15, row = quad*4 + reg
#pragma unroll
    for (int rt = 0; rt < 2; rt++)
#pragma unroll
        for (int ntl = 0; ntl < 2; ntl++) {
            const int c = (w * 2 + ntl) * 16 + m16;
#pragma unroll
            for (int reg = 0; reg < 4; reg++) {
                const size_t row = (size_t)(e0 + rt * 16 + quad * 4 + reg);
                Y2[row * DIM + c] = acc[rt][ntl][reg];
            }
        }
}

// ===========================================================================
// msg kernel: agg[d] = sum_{p: second[p]=d} selu(h[first_p]@W_top + Y2[d] + b)
// Block 256 thr (4 waves), M=128 pairs (6250 blocks), N=128, K=128.
// Wave w owns ONLY its 32 rows (w*32..+31) x all 8 nt: zero A redundancy,
// B shared across waves (L1-hot). No k-loop LDS/barriers.
// Epilogue: selu+Y2+bias in registers -> per-run segmented sums via 2x
// shfl_xor -> plain store (interior run) / atomicAdd (wave-boundary run).
// ===========================================================================
__global__ __launch_bounds__(256, 3)
void msg_kernel(const ushort_t* __restrict__ hbh, const ushort_t* __restrict__ hbl,
                const int* __restrict__ sfirst, const int* __restrict__ ssecond,
                const ushort_t* __restrict__ wt, const float* __restrict__ Y2,
                const float* __restrict__ bmsg, float* __restrict__ agg)
{
    __shared__ int f_s[128];
    __shared__ int s_sh[128];

    const int tid  = threadIdx.x;
    const int lane = tid & 63;
    const int w    = tid >> 6;
    const int p0   = blockIdx.x * 128;

    if (tid < 128) {
        f_s[tid]  = sfirst[p0 + tid];
        s_sh[tid] = ssecond[p0 + tid];
    }
    __syncthreads();

    const int m16  = lane & 15;
    const int quad = lane >> 4;
    const int r0   = f_s[w * 32 + m16];
    const int r1   = f_s[w * 32 + 16 + m16];

    f32x4 acc[2][8];
#pragma unroll
    for (int rt = 0; rt < 2; rt++)
#pragma unroll
        for (int nt = 0; nt < 8; nt++) acc[rt][nt] = {};

#pragma unroll
    for (int ks = 0; ks < 4; ks++) {
        const int koff = ks * 32 + quad * 8;
        const bf16x8 a0h = *(const bf16x8*)(hbh + (size_t)r0 * DIM + koff);
        const bf16x8 a0l = *(const bf16x8*)(hbl + (size_t)r0 * DIM + koff);
        const bf16x8 a1h = *(const bf16x8*)(hbh + (size_t)r1 * DIM + koff);
        const bf16x8 a1l = *(const bf16x8*)(hbl + (size_t)r1 * DIM + koff);
#pragma unroll
        for (int nt = 0; nt < 8; nt++) {
            const bf16x8 bh = *(const bf16x8*)(wt + (size_t)(((ks * 2 + 0) * 8 + nt) * 64 + lane) * 8);
            const bf16x8 bl = *(const bf16x8*)(wt + (size_t)(((ks * 2 + 1) * 8 + nt) * 64 + lane) * 8);
            acc[0][nt] = __builtin_amdgcn_mfma_f32_16x16x32_bf16(a0h, bh, acc[0][nt], 0, 0, 0);
            acc[0][nt] = __builtin_amdgcn_mfma_f32_16x16x32_bf16(a0l, bh, acc[0][nt], 0, 0, 0);
            acc[0][nt] = __builtin_amdgcn_mfma_f32_16x16x32_bf16(a0h, bl, acc[0][nt], 0, 0, 0);
            acc[1][nt] = __builtin_amdgcn_mfma_f32_16x16x32_bf16(a1h, bh, acc[1][nt], 0, 0, 0);
            acc[1][nt] = __builtin_amdgcn_mfma_f32_16x16x32_bf16(a1l, bh, acc[1][nt], 0, 0, 0);
            acc[1][nt] = __builtin_amdgcn_mfma_f32_16x16x32_bf16(a1h, bl, acc[1][nt], 0, 0, 0);
        }
    }

    // ---- transform: val = selu(acc + Y2[dest_row] + bias) ----
    float bb[8];
#pragma unroll
    for (int nt = 0; nt < 8; nt++) bb[nt] = bmsg[nt * 16 + m16];

#pragma unroll
    for (int rt = 0; rt < 2; rt++) {
#pragma unroll
        for (int reg = 0; reg < 4; reg++) {
            const int row_l = w * 32 + rt * 16 + quad * 4 + reg;
            const int d = s_sh[row_l];
            const float* y2row = Y2 + (size_t)d * DIM;
#pragma unroll
            for (int nt = 0; nt < 8; nt++) {
                acc[rt][nt][reg] = selu_f(acc[rt][nt][reg] + y2row[nt * 16 + m16] + bb[nt]);
            }
        }
    }

    // ---- per-run segmented sums over the wave's 32 rows ----
    const int wbase = p0 + w * 32;
    const int s_before = (wbase == 0) ? -1 : ssecond[wbase - 1];
    const int s_after  = (wbase + 32 >= P_NUM) ? -1 : ssecond[wbase + 32];

    int start = 0;
    while (start < 32) {
        const int d = s_sh[w * 32 + start];
        int end = start + 1;
        while (end < 32 && s_sh[w * 32 + end] == d) end++;
        const bool atom = (start == 0 && d == s_before) ||
                          (end == 32 && d == s_after);
#pragma unroll
        for (int nt = 0; nt < 8; nt++) {
            float part = 0.f;
#pragma unroll
            for (int reg = 0; reg < 4; reg++) {
                const int ra = quad * 4 + reg;
                const int rb = 16 + ra;
                part += (ra >= start && ra < end) ? acc[0][nt][reg] : 0.f;
                part += (rb >= start && rb < end) ? acc[1][nt][reg] : 0.f;
            }
            part += __shfl_xor(part, 16, 64);
            part += __shfl_xor(part, 32, 64);
            if (lane < 16) {
                float* dst = agg + (size_t)d * DIM + nt * 16 + lane;
                if (atom) atomicAdd(dst, part);
                else      *dst = part;
            }
        }
        start = end;
    }
}

// ===========================================================================
// GRU kernel, register-gates: wave w owns nt {w, w+8, w+16} so z/r/h of
// column c = w*16 + (lane&15) live in the same thread -> no LDS exchange.
// Block 512 thr (8 waves), M=64 edges (1563 blocks, tail-guarded). z/r accs
// merge x@K and h@U; h-gate keeps xh/rh separate. One barrier (in-place h).
// ===========================================================================
__global__ __launch_bounds__(512, 3)
void gru_kernel(const float* __restrict__ agg,
                ushort_t* __restrict__ hbh, ushort_t* __restrict__ hbl,
                const ushort_t* __restrict__ wb, const float* __restrict__ bias)
{
    const int tid  = threadIdx.x;
    const int lane = tid & 63;
    const int w    = tid >> 6;          // 0..7
    const int e0   = blockIdx.x * 64;
    const int m16  = lane & 15;
    const int quad = lane >> 4;

    f32x4 az[4] = {}, ar[4] = {}, ahx[4] = {}, ahh[4] = {};

#define WB(ks_, gm_, cp_, nt_) \
    (*(const bf16x8*)(wb + ((size_t)(((ks_) * 96) + (gm_) * 48 + (cp_) * 24 + (nt_)) * 64 + lane) * 8))

#pragma unroll
    for (int ks = 0; ks < 4; ks++) {
        const int koff = ks * 32 + quad * 8;
        // B frags (shared across all 4 row-tiles)
        const bf16x8 KzH = WB(ks, 0, 0, w),      KzL = WB(ks, 0, 1, w);
        const bf16x8 UzH = WB(ks, 1, 0, w),      UzL = WB(ks, 1, 1, w);
        const bf16x8 KrH = WB(ks, 0, 0, w + 8),  KrL = WB(ks, 0, 1, w + 8);
        const bf16x8 UrH = WB(ks, 1, 0, w + 8),  UrL = WB(ks, 1, 1, w + 8);
        const bf16x8 KhH = WB(ks, 0, 0, w + 16), KhL = WB(ks, 0, 1, w + 16);
        const bf16x8 UhH = WB(ks, 1, 0, w + 16), UhL = WB(ks, 1, 1, w + 16);
#pragma unroll
        for (int rt = 0; rt < 4; rt++) {
            int row = e0 + rt * 16 + m16;
            if (row >= E_NUM) row = E_NUM - 1;
            const float* xp = agg + (size_t)row * DIM + koff;
            const float4 v0 = *(const float4*)xp;
            const float4 v1 = *(const float4*)(xp + 4);
            const float xv[8] = {v0.x, v0.y, v0.z, v0.w, v1.x, v1.y, v1.z, v1.w};
            bf16x8 xh, xl;
#pragma unroll
            for (int j = 0; j < 8; j++) {
                const ushort_t hi = f2bf(xv[j]);
                xh[j] = (short)hi;
                xl[j] = (short)f2bf(xv[j] - bf2f(hi));
            }
            const bf16x8 hh = *(const bf16x8*)(hbh + (size_t)row * DIM + koff);
            const bf16x8 hl = *(const bf16x8*)(hbl + (size_t)row * DIM + koff);

            az[rt] = __builtin_amdgcn_mfma_f32_16x16x32_bf16(xh, KzH, az[rt], 0, 0, 0);
            az[rt] = __builtin_amdgcn_mfma_f32_16x16x32_bf16(xl, KzH, az[rt], 0, 0, 0);
            az[rt] = __builtin_amdgcn_mfma_f32_16x16x32_bf16(xh, KzL, az[rt], 0, 0, 0);
            az[rt] = __builtin_amdgcn_mfma_f32_16x16x32_bf16(hh, UzH, az[rt], 0, 0, 0);
            az[rt] = __builtin_amdgcn_mfma_f32_16x16x32_bf16(hl, UzH, az[rt], 0, 0, 0);
            az[rt] = __builtin_amdgcn_mfma_f32_16x16x32_bf16(hh, UzL, az[rt], 0, 0, 0);

            ar[rt] = __builtin_amdgcn_mfma_f32_16x16x32_bf16(xh, KrH, ar[rt], 0, 0, 0);
            ar[rt] = __builtin_amdgcn_mfma_f32_16x16x32_bf16(xl, KrH, ar[rt], 0, 0, 0);
            ar[rt] = __builtin_amdgcn_mfma_f32_16x16x32_bf16(xh, KrL, ar[rt], 0, 0, 0);
            ar[rt] = __builtin_amdgcn_mfma_f32_16x16x32_bf16(hh, UrH, ar[rt], 0, 0, 0);
            ar[rt] = __builtin_amdgcn_mfma_f32_16x16x32_bf16(hl, UrH, ar[rt], 0, 0, 0);
            ar[rt] = __builtin_amdgcn_mfma_f32_16x16x32_bf16(hh, UrL, ar[rt], 0, 0, 0);

            ahx[rt] = __builtin_amdgcn_mfma_f32_16x16x32_bf16(xh, KhH, ahx[rt], 0, 0, 0);
            ahx[rt] = __builtin_amdgcn_mfma_f32_16x16x32_bf16(xl, KhH, ahx[rt], 0, 0, 0);
            ahx[rt] = __builtin_amdgcn_mfma_f32_16x16x32_bf16(xh, KhL, ahx[rt], 0, 0, 0);
            ahh[rt] = __builtin_amdgcn_mfma_f32_16x16x32_bf16(hh, UhH, ahh[rt], 0, 0, 0);
            ahh[rt] = __builtin_amdgcn_mfma_f32_16x16x32_bf16(hl, UhH, ahh[rt], 0, 0, 0);
            ahh[rt] = __builtin_amdgcn_mfma_f32_16x16x32_bf16(hh, UhL, ahh[rt], 0, 0, 0);
        }
    }
#undef WB

    __syncthreads();   // all reads of hbh/hbl done before in-place writes

    const int c = w * 16 + m16;
    const float bz  = bias[c] + bias[384 + c];
    const float br  = bias[128 + c] + bias[512 + c];
    const float bxh = bias[256 + c];
    const float brh = bias[640 + c];

#pragma unroll
    for (int rt = 0; rt < 4; rt++) {
#pragma unroll
        for (int reg = 0; reg < 4; reg++) {
            const int row = e0 + rt * 16 + quad * 4 + reg;
            if (row < E_NUM) {
                const float z  = 1.f / (1.f + expf(-(az[rt][reg] + bz)));
                const float r  = 1.f / (1.f + expf(-(ar[rt][reg] + br)));
                const float hc = tanhf(ahx[rt][reg] + bxh + r * (ahh[rt][reg] + brh));
                const size_t g = (size_t)row * DIM + c;
                const float hp = bf2f(hbh[g]) + bf2f(hbl[g]);
                const float hn = z * hp + (1.f - z) * hc;
                const ushort_t hi = f2bf(hn);
                hbh[g] = hi;
                hbl[g] = f2bf(hn - bf2f(hi));
            }
        }
    }
}

// ===========================================================================
// Graph pooling + readout
// ===========================================================================
__global__ __launch_bounds__(256)
void pool_kernel(const ushort_t* __restrict__ hbh, const ushort_t* __restrict__ hbl,
                 const int* __restrict__ gid, float* __restrict__ pooled)
{
    const int idx = blockIdx.x * 256 + threadIdx.x;
    const int e = idx >> 7;
    const int n = idx & 127;
    const float hv = bf2f(hbh[idx]) + bf2f(hbl[idx]);
    atomicAdd(pooled + (size_t)gid[e] * DIM + n, hv);
}

__global__ __launch_bounds__(256)
void readout_kernel(const float* __restrict__ pooled,
                    const float* __restrict__ W1, const float* __restrict__ b1,
                    const float* __restrict__ W2, const float* __restrict__ b2,
                    const float* __restrict__ W3, const float* __restrict__ b3,
                    float* __restrict__ out)
{
    __shared__ float sp[DIM];
    __shared__ float s1[R_UNITS];
    __shared__ float s2[R_UNITS];
    const int g = blockIdx.x, tid = threadIdx.x;

    if (tid < DIM) sp[tid] = pooled[(size_t)g * DIM + tid];
    __syncthreads();

    float acc = b1[tid];
    for (int k = 0; k < DIM; k++) acc += sp[k] * W1[(size_t)k * R_UNITS + tid];
    s1[tid] = selu_f(acc);
    __syncthreads();

    acc = b2[tid];
    for (int k = 0; k < R_UNITS; k++) acc += s1[k] * W2[(size_t)k * R_UNITS + tid];
    s2[tid] = selu_f(acc) * W3[tid];
    __syncthreads();

    for (int s = 128; s > 0; s >>= 1) {
        if (tid < s) s2[tid] += s2[tid + s];
        __syncthreads();
    }
    if (tid == 0) out[g] = s2[0] + b3[0];
}

// ===========================================================================
extern "C" void kernel_launch(void* const* d_in, const int* in_sizes, int n_in,
                              void* d_out, int out_size, void* d_ws, size_t ws_size,
                              hipStream_t stream)
{
    const float* link_state = (const float*)d_in[0];
    const int*   gids       = (const int*)d_in[1];
    const int*   first      = (const int*)d_in[2];
    const int*   second     = (const int*)d_in[3];
    const float* Wmsg       = (const float*)d_in[5];
    const float* bmsg       = (const float*)d_in[6];
    const float* gK         = (const float*)d_in[7];
    const float* gU         = (const float*)d_in[8];
    const float* gbias      = (const float*)d_in[9];
    const float* W1         = (const float*)d_in[10];
    const float* b1         = (const float*)d_in[11];
    const float* W2         = (const float*)d_in[12];
    const float* b2         = (const float*)d_in[13];
    const float* W3         = (const float*)d_in[14];
    const float* b3         = (const float*)d_in[15];
    float* out = (float*)d_out;

    // ws layout (16B-aligned segments), ~154 MiB total:
    //   offsets[100004] counts[1e5] cursor[1e5] bsum[128] sfirst[P] ssecond[P]
    //   wt[32768 us] wy[32768 us] wb[196608 us]
    //   hb_hi[E*128 us] hb_lo[E*128 us] agg[E*128 f32] Y2[E*128 f32]
    int* offsets = (int*)d_ws;
    int* counts  = offsets + 100004;
    int* cursor  = counts + E_NUM;
    int* bsum    = cursor + E_NUM;
    int* sfirst  = bsum + 128;                 // pad keeps 16B alignment
    int* ssecond = sfirst + P_NUM;
    ushort_t* wt    = (ushort_t*)(ssecond + P_NUM);
    ushort_t* wy    = wt + 32768;
    ushort_t* wb    = wy + 32768;
    ushort_t* hb_hi = wb + 196608;
    ushort_t* hb_lo = hb_hi + (size_t)E_NUM * DIM;
    float*    agg   = (float*)(hb_lo + (size_t)E_NUM * DIM);
    float*    Y2    = agg + (size_t)E_NUM * DIM;

    const size_t agg_bytes = (size_t)E_NUM * DIM * sizeof(float);

    // ---- one-time prep ----
    hipMemsetAsync(counts, 0, E_NUM * sizeof(int), stream);
    hipMemsetAsync(cursor, 0, E_NUM * sizeof(int), stream);
    hist_kernel<<<P_NUM / 256, 256, 0, stream>>>(second, counts);
    scanA_kernel<<<98, 1024, 0, stream>>>(counts, offsets, bsum);
    scanB_kernel<<<1, 1, 0, stream>>>(bsum, offsets);
    scanC_kernel<<<98, 1024, 0, stream>>>(offsets, bsum);
    fill_kernel<<<P_NUM / 256, 256, 0, stream>>>(first, second, offsets, cursor,
                                                 sfirst, ssecond);
    wsplit_build_kernel<<<32, 256, 0, stream>>>(Wmsg, wt, wy);
    wb_build_kernel<<<96, 256, 0, stream>>>(gK, gU, wb);
    cast_h_kernel<<<(E_NUM * DIM) / 256, 256, 0, stream>>>(link_state, hb_hi, hb_lo);

    // ---- message-passing steps ----
    for (int t = 0; t < T_STEPS; t++) {
        y2_kernel<<<E_NUM / 32, 256, 0, stream>>>(hb_hi, hb_lo, wy, Y2);
        hipMemsetAsync(agg, 0, agg_bytes, stream);
        msg_kernel<<<P_NUM / 128, 256, 0, stream>>>(hb_hi, hb_lo, sfirst, ssecond,
                                                    wt, Y2, bmsg, agg);
        gru_kernel<<<(E_NUM + 63) / 64, 512, 0, stream>>>(agg, hb_hi, hb_lo,
                                                          wb, gbias);
    }

    // ---- pool + readout ----
    float* pooled = agg;  // reuse
    hipMemsetAsync(pooled, 0, (size_t)G_NUM * DIM * sizeof(float), stream);
    pool_kernel<<<(E_NUM * DIM) / 256, 256, 0, stream>>>(hb_hi, hb_lo, gids, pooled);
    readout_kernel<<<G_NUM, 256, 0, stream>>>(pooled, W1, b1, W2, b2, W3, b3, out);
}

// Round 9
// 4782.892 us; speedup vs baseline: 1.2334x; 1.0252x over previous
//
#include <hip/hip_runtime.h>
#include <math.h>

#define DIM 128
#define E_NUM 100000
#define P_NUM 800000
#define G_NUM 1000
#define T_STEPS 8
#define R_UNITS 256

typedef __attribute__((ext_vector_type(8))) short bf16x8;   // 8 bf16 = 4 VGPRs
typedef __attribute__((ext_vector_type(4))) float f32x4;    // 16x16 MFMA acc

typedef unsigned short ushort_t;
typedef unsigned int   uint_t;

__device__ __forceinline__ float selu_f(float x) {
    const float alpha = 1.6732632423543772f;
    const float scale = 1.0507009873554805f;
    return x > 0.f ? scale * x : scale * alpha * expm1f(x);
}

__device__ __forceinline__ ushort_t f2bf(float x) {
    uint_t u = __float_as_uint(x);
    uint_t r = (u + 0x7fffu + ((u >> 16) & 1u)) >> 16;
    return (ushort_t)r;
}
__device__ __forceinline__ float bf2f(ushort_t h) {
    return __uint_as_float(((uint_t)h) << 16);
}

// ===========================================================================
// CSR build (once per launch). Multi-block scan.
// ===========================================================================
__global__ __launch_bounds__(256)
void hist_kernel(const int* __restrict__ second, int* __restrict__ counts)
{
    const int p = blockIdx.x * 256 + threadIdx.x;
    atomicAdd(&counts[second[p]], 1);
}

__global__ __launch_bounds__(1024)
void scanA_kernel(const int* __restrict__ counts, int* __restrict__ offsets,
                  int* __restrict__ bsum)
{
    __shared__ int buf[1024];
    const int i = blockIdx.x * 1024 + threadIdx.x;
    const int v = (i < E_NUM) ? counts[i] : 0;
    buf[threadIdx.x] = v;
    __syncthreads();
    for (int off = 1; off < 1024; off <<= 1) {
        const int t = (threadIdx.x >= off) ? buf[threadIdx.x - off] : 0;
        __syncthreads();
        buf[threadIdx.x] += t;
        __syncthreads();
    }
    if (i < E_NUM) offsets[i] = buf[threadIdx.x] - v;   // block-local exclusive
    if (threadIdx.x == 1023) bsum[blockIdx.x] = buf[1023];
}

__global__ void scanB_kernel(int* __restrict__ bsum, int* __restrict__ offsets)
{
    int acc = 0;
    for (int b = 0; b < 98; b++) { const int t = bsum[b]; bsum[b] = acc; acc += t; }
    offsets[E_NUM] = P_NUM;
}

__global__ __launch_bounds__(1024)
void scanC_kernel(int* __restrict__ offsets, const int* __restrict__ bsum)
{
    const int i = blockIdx.x * 1024 + threadIdx.x;
    if (i < E_NUM) offsets[i] += bsum[blockIdx.x];
}

__global__ __launch_bounds__(256)
void fill_kernel(const int* __restrict__ first, const int* __restrict__ second,
                 const int* __restrict__ offsets, int* __restrict__ cursor,
                 int* __restrict__ sfirst, int* __restrict__ ssecond)
{
    const int p = blockIdx.x * 256 + threadIdx.x;
    const int d = second[p];
    const int pos = atomicAdd(&cursor[d], 1);
    const int idx = offsets[d] + pos;
    sfirst[idx] = first[p];
    ssecond[idx] = d;
}

// ===========================================================================
// One-time prep (same as R8).
// ===========================================================================
__global__ __launch_bounds__(256)
void cast_h_kernel(const float* __restrict__ src,
                   ushort_t* __restrict__ dhi, ushort_t* __restrict__ dlo)
{
    const int idx = blockIdx.x * 256 + threadIdx.x;
    const float x = src[idx];
    const ushort_t hi = f2bf(x);
    dhi[idx] = hi;
    dlo[idx] = f2bf(x - bf2f(hi));
}

__global__ __launch_bounds__(256)
void wsplit_build_kernel(const float* __restrict__ Wmsg,
                         ushort_t* __restrict__ wt, ushort_t* __restrict__ wy)
{
    const int idx  = blockIdx.x * 256 + threadIdx.x;   // 8192 slots (2 halves)
    const int lane = idx & 63;
    const int nt   = (idx >> 6) & 7;
    const int comp = (idx >> 9) & 1;
    const int ks   = (idx >> 10) & 3;
    const int half = idx >> 12;
    const int n    = nt * 16 + (lane & 15);
    const int kb   = ks * 32 + (lane >> 4) * 8 + half * 128;
    ushort_t* dst  = half ? wy : wt;
    const int slot = idx & 4095;
#pragma unroll
    for (int j = 0; j < 8; j++) {
        const float w = Wmsg[(size_t)(kb + j) * DIM + n];
        const ushort_t hi = f2bf(w);
        dst[(size_t)slot * 8 + j] = comp ? f2bf(w - bf2f(hi)) : hi;
    }
}

__global__ __launch_bounds__(256)
void wb_build_kernel(const float* __restrict__ K, const float* __restrict__ U,
                     ushort_t* __restrict__ wb)
{
    const int idx  = blockIdx.x * 256 + threadIdx.x;   // 24576 slots
    const int lane = idx & 63;
    int t = idx >> 6;
    const int nt   = t % 24;  t /= 24;
    const int comp = t & 1;   t >>= 1;
    const int gemm = t & 1;
    const int ks   = t >> 1;
    const float* src = gemm ? U : K;
    const int n  = nt * 16 + (lane & 15);
    const int kb = ks * 32 + (lane >> 4) * 8;
#pragma unroll
    for (int j = 0; j < 8; j++) {
        const float w = src[(size_t)(kb + j) * 384 + n];
        const ushort_t hi = f2bf(w);
        wb[(size_t)idx * 8 + j] = comp ? f2bf(w - bf2f(hi)) : hi;
    }
}

// ===========================================================================
// Y2 kernel: Y2 = h @ W_bot  [E x 128] (same as R8).
// ===========================================================================
__global__ __launch_bounds__(256, 4)
void y2_kernel(const ushort_t* __restrict__ hbh, const ushort_t* __restrict__ hbl,
               const ushort_t* __restrict__ wy, float* __restrict__ Y2)
{
    const int tid  = threadIdx.x;
    const int lane = tid & 63;
    const int w    = tid >> 6;
    const int e0   = blockIdx.x * 32;
    const int m16  = lane & 15;
    const int quad = lane >> 4;

    f32x4 acc[2][2] = {};
#pragma unroll
    for (int ks = 0; ks < 4; ks++) {
        const int koff = ks * 32 + quad * 8;
        bf16x8 ah[2], al[2];
#pragma unroll
        for (int rt = 0; rt < 2; rt++) {
            const size_t row = (size_t)(e0 + rt * 16 + m16);
            ah[rt] = *(const bf16x8*)(hbh + row * DIM + koff);
            al[rt] = *(const bf16x8*)(hbl + row * DIM + koff);
        }
#pragma unroll
        for (int ntl = 0; ntl < 2; ntl++) {
            const int nt = w * 2 + ntl;
            const bf16x8 bh = *(const bf16x8*)(wy + (size_t)(((ks * 2 + 0) * 8 + nt) * 64 + lane) * 8);
            const bf16x8 bl = *(const bf16x8*)(wy + (size_t)(((ks * 2 + 1) * 8 + nt) * 64 + lane) * 8);
#pragma unroll
            for (int rt = 0; rt < 2; rt++) {
                acc[rt][ntl] = __builtin_amdgcn_mfma_f32_16x16x32_bf16(ah[rt], bh, acc[rt][ntl], 0, 0, 0);
                acc[rt][ntl] = __builtin_amdgcn_mfma_f32_16x16x32_bf16(al[rt], bh, acc[rt][ntl], 0, 0, 0);
                acc[rt][ntl] = __builtin_amdgcn_mfma_f32_16x16x32_bf16(ah[rt], bl, acc[rt][ntl], 0, 0, 0);
            }
        }
    }
#pragma unroll
    for (int rt = 0; rt < 2; rt++)
#pragma unroll
        for (int ntl = 0; ntl < 2; ntl++) {
            const int c = (w * 2 + ntl) * 16 + m16;
#pragma unroll
            for (int reg = 0; reg < 4; reg++) {
                const size_t row = (size_t)(e0 + rt * 16 + quad * 4 + reg);
                Y2[row * DIM + c] = acc[rt][ntl][reg];
            }
        }
}

// ===========================================================================
// msg kernel: agg[d] = sum_{p: second[p]=d} selu(h[first_p]@W_top + Y2[d] + b)
// R9 change: ALL 16 A-gathers (4ks x 2comp x 2rows) hoisted into registers
// before any MFMA — 16 independent vmem loads batch into one deep vmcnt
// pipeline (~128 in-flight misses/CU at 8 waves) instead of ~2/wave.
// (256,2): VGPR budget 256 holds A-buf(64) + acc(64) + B + addressing.
// ===========================================================================
__global__ __launch_bounds__(256, 2)
void msg_kernel(const ushort_t* __restrict__ hbh, const ushort_t* __restrict__ hbl,
                const int* __restrict__ sfirst, const int* __restrict__ ssecond,
                const ushort_t* __restrict__ wt, const float* __restrict__ Y2,
                const float* __restrict__ bmsg, float* __restrict__ agg)
{
    __shared__ int f_s[128];
    __shared__ int s_sh[128];

    const int tid  = threadIdx.x;
    const int lane = tid & 63;
    const int w    = tid >> 6;
    const int p0   = blockIdx.x * 128;

    if (tid < 128) {
        f_s[tid]  = sfirst[p0 + tid];
        s_sh[tid] = ssecond[p0 + tid];
    }
    __syncthreads();

    const int m16  = lane & 15;
    const int quad = lane >> 4;
    const int r0   = f_s[w * 32 + m16];
    const int r1   = f_s[w * 32 + 16 + m16];

    // ---- batched A-gather: 16 independent 16B loads, no consumers between ----
    bf16x8 A0h[4], A0l[4], A1h[4], A1l[4];
    {
        const ushort_t* b0 = hbh + (size_t)r0 * DIM;
        const ushort_t* l0 = hbl + (size_t)r0 * DIM;
        const ushort_t* b1 = hbh + (size_t)r1 * DIM;
        const ushort_t* l1 = hbl + (size_t)r1 * DIM;
        const int q8 = quad * 8;
#pragma unroll
        for (int ks = 0; ks < 4; ks++) {
            const int koff = ks * 32 + q8;
            A0h[ks] = *(const bf16x8*)(b0 + koff);
            A0l[ks] = *(const bf16x8*)(l0 + koff);
            A1h[ks] = *(const bf16x8*)(b1 + koff);
            A1l[ks] = *(const bf16x8*)(l1 + koff);
        }
    }

    f32x4 acc[2][8];
#pragma unroll
    for (int rt = 0; rt < 2; rt++)
#pragma unroll
        for (int nt = 0; nt < 8; nt++) acc[rt][nt] = {};

#pragma unroll
    for (int ks = 0; ks < 4; ks++) {
#pragma unroll
        for (int nt = 0; nt < 8; nt++) {
            const bf16x8 bh = *(const bf16x8*)(wt + (size_t)(((ks * 2 + 0) * 8 + nt) * 64 + lane) * 8);
            const bf16x8 bl = *(const bf16x8*)(wt + (size_t)(((ks * 2 + 1) * 8 + nt) * 64 + lane) * 8);
            acc[0][nt] = __builtin_amdgcn_mfma_f32_16x16x32_bf16(A0h[ks], bh, acc[0][nt], 0, 0, 0);
            acc[0][nt] = __builtin_amdgcn_mfma_f32_16x16x32_bf16(A0l[ks], bh, acc[0][nt], 0, 0, 0);
            acc[0][nt] = __builtin_amdgcn_mfma_f32_16x16x32_bf16(A0h[ks], bl, acc[0][nt], 0, 0, 0);
            acc[1][nt] = __builtin_amdgcn_mfma_f32_16x16x32_bf16(A1h[ks], bh, acc[1][nt], 0, 0, 0);
            acc[1][nt] = __builtin_amdgcn_mfma_f32_16x16x32_bf16(A1l[ks], bh, acc[1][nt], 0, 0, 0);
            acc[1][nt] = __builtin_amdgcn_mfma_f32_16x16x32_bf16(A1h[ks], bl, acc[1][nt], 0, 0, 0);
        }
    }

    // ---- transform: val = selu(acc + Y2[dest_row] + bias) ----
    float bb[8];
#pragma unroll
    for (int nt = 0; nt < 8; nt++) bb[nt] = bmsg[nt * 16 + m16];

#pragma unroll
    for (int rt = 0; rt < 2; rt++) {
#pragma unroll
        for (int reg = 0; reg < 4; reg++) {
            const int row_l = w * 32 + rt * 16 + quad * 4 + reg;
            const int d = s_sh[row_l];
            const float* y2row = Y2 + (size_t)d * DIM;
#pragma unroll
            for (int nt = 0; nt < 8; nt++) {
                acc[rt][nt][reg] = selu_f(acc[rt][nt][reg] + y2row[nt * 16 + m16] + bb[nt]);
            }
        }
    }

    // ---- per-run segmented sums over the wave's 32 rows ----
    const int wbase = p0 + w * 32;
    const int s_before = (wbase == 0) ? -1 : ssecond[wbase - 1];
    const int s_after  = (wbase + 32 >= P_NUM) ? -1 : ssecond[wbase + 32];

    int start = 0;
    while (start < 32) {
        const int d = s_sh[w * 32 + start];
        int end = start + 1;
        while (end < 32 && s_sh[w * 32 + end] == d) end++;
        const bool atom = (start == 0 && d == s_before) ||
                          (end == 32 && d == s_after);
#pragma unroll
        for (int nt = 0; nt < 8; nt++) {
            float part = 0.f;
#pragma unroll
            for (int reg = 0; reg < 4; reg++) {
                const int ra = quad * 4 + reg;
                const int rb = 16 + ra;
                part += (ra >= start && ra < end) ? acc[0][nt][reg] : 0.f;
                part += (rb >= start && rb < end) ? acc[1][nt][reg] : 0.f;
            }
            part += __shfl_xor(part, 16, 64);
            part += __shfl_xor(part, 32, 64);
            if (lane < 16) {
                float* dst = agg + (size_t)d * DIM + nt * 16 + lane;
                if (atom) atomicAdd(dst, part);
                else      *dst = part;
            }
        }
        start = end;
    }
}

// ===========================================================================
// GRU kernel, register-gates (same as R8).
// ===========================================================================
__global__ __launch_bounds__(512, 3)
void gru_kernel(const float* __restrict__ agg,
                ushort_t* __restrict__ hbh, ushort_t* __restrict__ hbl,
                const ushort_t* __restrict__ wb, const float* __restrict__ bias)
{
    const int tid  = threadIdx.x;
    const int lane = tid & 63;
    const int w    = tid >> 6;          // 0..7
    const int e0   = blockIdx.x * 64;
    const int m16  = lane & 15;
    const int quad = lane >> 4;

    f32x4 az[4] = {}, ar[4] = {}, ahx[4] = {}, ahh[4] = {};

#define WB(ks_, gm_, cp_, nt_) \
    (*(const bf16x8*)(wb + ((size_t)(((ks_) * 96) + (gm_) * 48 + (cp_) * 24 + (nt_)) * 64 + lane) * 8))

#pragma unroll
    for (int ks = 0; ks < 4; ks++) {
        const int koff = ks * 32 + quad * 8;
        const bf16x8 KzH = WB(ks, 0, 0, w),      KzL = WB(ks, 0, 1, w);
        const bf16x8 UzH = WB(ks, 1, 0, w),      UzL = WB(ks, 1, 1, w);
        const bf16x8 KrH = WB(ks, 0, 0, w + 8),  KrL = WB(ks, 0, 1, w + 8);
        const bf16x8 UrH = WB(ks, 1, 0, w + 8),  UrL = WB(ks, 1, 1, w + 8);
        const bf16x8 KhH = WB(ks, 0, 0, w + 16), KhL = WB(ks, 0, 1, w + 16);
        const bf16x8 UhH = WB(ks, 1, 0, w + 16), UhL = WB(ks, 1, 1, w + 16);
#pragma unroll
        for (int rt = 0; rt < 4; rt++) {
            int row = e0 + rt * 16 + m16;
            if (row >= E_NUM) row = E_NUM - 1;
            const float* xp = agg + (size_t)row * DIM + koff;
            const float4 v0 = *(const float4*)xp;
            const float4 v1 = *(const float4*)(xp + 4);
            const float xv[8] = {v0.x, v0.y, v0.z, v0.w, v1.x, v1.y, v1.z, v1.w};
            bf16x8 xh, xl;
#pragma unroll
            for (int j = 0; j < 8; j++) {
                const ushort_t hi = f2bf(xv[j]);
                xh[j] = (short)hi;
                xl[j] = (short)f2bf(xv[j] - bf2f(hi));
            }
            const bf16x8 hh = *(const bf16x8*)(hbh + (size_t)row * DIM + koff);
            const bf16x8 hl = *(const bf16x8*)(hbl + (size_t)row * DIM + koff);

            az[rt] = __builtin_amdgcn_mfma_f32_16x16x32_bf16(xh, KzH, az[rt], 0, 0, 0);
            az[rt] = __builtin_amdgcn_mfma_f32_16x16x32_bf16(xl, KzH, az[rt], 0, 0, 0);
            az[rt] = __builtin_amdgcn_mfma_f32_16x16x32_bf16(xh, KzL, az[rt], 0, 0, 0);
            az[rt] = __builtin_amdgcn_mfma_f32_16x16x32_bf16(hh, UzH, az[rt], 0, 0, 0);
            az[rt] = __builtin_amdgcn_mfma_f32_16x16x32_bf16(hl, UzH, az[rt], 0, 0, 0);
            az[rt] = __builtin_amdgcn_mfma_f32_16x16x32_bf16(hh, UzL, az[rt], 0, 0, 0);

            ar[rt] = __builtin_amdgcn_mfma_f32_16x16x32_bf16(xh, KrH, ar[rt], 0, 0, 0);
            ar[rt] = __builtin_amdgcn_mfma_f32_16x16x32_bf16(xl, KrH, ar[rt], 0, 0, 0);
            ar[rt] = __builtin_amdgcn_mfma_f32_16x16x32_bf16(xh, KrL, ar[rt], 0, 0, 0);
            ar[rt] = __builtin_amdgcn_mfma_f32_16x16x32_bf16(hh, UrH, ar[rt], 0, 0, 0);
            ar[rt] = __builtin_amdgcn_mfma_f32_16x16x32_bf16(hl, UrH, ar[rt], 0, 0, 0);
            ar[rt] = __builtin_amdgcn_mfma_f32_16x16x32_bf16(hh, UrL, ar[rt], 0, 0, 0);

            ahx[rt] = __builtin_amdgcn_mfma_f32_16x16x32_bf16(xh, KhH, ahx[rt], 0, 0, 0);
            ahx[rt] = __builtin_amdgcn_mfma_f32_16x16x32_bf16(xl, KhH, ahx[rt], 0, 0, 0);
            ahx[rt] = __builtin_amdgcn_mfma_f32_16x16x32_bf16(xh, KhL, ahx[rt], 0, 0, 0);
            ahh[rt] = __builtin_amdgcn_mfma_f32_16x16x32_bf16(hh, UhH, ahh[rt], 0, 0, 0);
            ahh[rt] = __builtin_amdgcn_mfma_f32_16x16x32_bf16(hl, UhH, ahh[rt], 0, 0, 0);
            ahh[rt] = __builtin_amdgcn_mfma_f32_16x16x32_bf16(hh, UhL, ahh[rt], 0, 0, 0);
        }
    }
#undef WB

    __syncthreads();   // all reads of hbh/hbl done before in-place writes

    const int c = w * 16 + m16;
    const float bz  = bias[c] + bias[384 + c];
    const float br  = bias[128 + c] + bias[512 + c];
    const float bxh = bias[256 + c];
    const float brh = bias[640 + c];

#pragma unroll
    for (int rt = 0; rt < 4; rt++) {
#pragma unroll
        for (int reg = 0; reg < 4; reg++) {
            const int row = e0 + rt * 16 + quad * 4 + reg;
            if (row < E_NUM) {
                const float z  = 1.f / (1.f + expf(-(az[rt][reg] + bz)));
                const float r  = 1.f / (1.f + expf(-(ar[rt][reg] + br)));
                const float hc = tanhf(ahx[rt][reg] + bxh + r * (ahh[rt][reg] + brh));
                const size_t g = (size_t)row * DIM + c;
                const float hp = bf2f(hbh[g]) + bf2f(hbl[g]);
                const float hn = z * hp + (1.f - z) * hc;
                const ushort_t hi = f2bf(hn);
                hbh[g] = hi;
                hbl[g] = f2bf(hn - bf2f(hi));
            }
        }
    }
}

// ===========================================================================
// Graph pooling + readout
// ===========================================================================
__global__ __launch_bounds__(256)
void pool_kernel(const ushort_t* __restrict__ hbh, const ushort_t* __restrict__ hbl,
                 const int* __restrict__ gid, float* __restrict__ pooled)
{
    const int idx = blockIdx.x * 256 + threadIdx.x;
    const int e = idx >> 7;
    const int n = idx & 127;
    const float hv = bf2f(hbh[idx]) + bf2f(hbl[idx]);
    atomicAdd(pooled + (size_t)gid[e] * DIM + n, hv);
}

__global__ __launch_bounds__(256)
void readout_kernel(const float* __restrict__ pooled,
                    const float* __restrict__ W1, const float* __restrict__ b1,
                    const float* __restrict__ W2, const float* __restrict__ b2,
                    const float* __restrict__ W3, const float* __restrict__ b3,
                    float* __restrict__ out)
{
    __shared__ float sp[DIM];
    __shared__ float s1[R_UNITS];
    __shared__ float s2[R_UNITS];
    const int g = blockIdx.x, tid = threadIdx.x;

    if (tid < DIM) sp[tid] = pooled[(size_t)g * DIM + tid];
    __syncthreads();

    float acc = b1[tid];
    for (int k = 0; k < DIM; k++) acc += sp[k] * W1[(size_t)k * R_UNITS + tid];
    s1[tid] = selu_f(acc);
    __syncthreads();

    acc = b2[tid];
    for (int k = 0; k < R_UNITS; k++) acc += s1[k] * W2[(size_t)k * R_UNITS + tid];
    s2[tid] = selu_f(acc) * W3[tid];
    __syncthreads();

    for (int s = 128; s > 0; s >>= 1) {
        if (tid < s) s2[tid] += s2[tid + s];
        __syncthreads();
    }
    if (tid == 0) out[g] = s2[0] + b3[0];
}

// ===========================================================================
extern "C" void kernel_launch(void* const* d_in, const int* in_sizes, int n_in,
                              void* d_out, int out_size, void* d_ws, size_t ws_size,
                              hipStream_t stream)
{
    const float* link_state = (const float*)d_in[0];
    const int*   gids       = (const int*)d_in[1];
    const int*   first      = (const int*)d_in[2];
    const int*   second     = (const int*)d_in[3];
    const float* Wmsg       = (const float*)d_in[5];
    const float* bmsg       = (const float*)d_in[6];
    const float* gK         = (const float*)d_in[7];
    const float* gU         = (const float*)d_in[8];
    const float* gbias      = (const float*)d_in[9];
    const float* W1         = (const float*)d_in[10];
    const float* b1         = (const float*)d_in[11];
    const float* W2         = (const float*)d_in[12];
    const float* b2         = (const float*)d_in[13];
    const float* W3         = (const float*)d_in[14];
    const float* b3         = (const float*)d_in[15];
    float* out = (float*)d_out;

    // ws layout (16B-aligned segments), ~154 MiB total:
    //   offsets[100004] counts[1e5] cursor[1e5] bsum[128] sfirst[P] ssecond[P]
    //   wt[32768 us] wy[32768 us] wb[196608 us]
    //   hb_hi[E*128 us] hb_lo[E*128 us] agg[E*128 f32] Y2[E*128 f32]
    int* offsets = (int*)d_ws;
    int* counts  = offsets + 100004;
    int* cursor  = counts + E_NUM;
    int* bsum    = cursor + E_NUM;
    int* sfirst  = bsum + 128;
    int* ssecond = sfirst + P_NUM;
    ushort_t* wt    = (ushort_t*)(ssecond + P_NUM);
    ushort_t* wy    = wt + 32768;
    ushort_t* wb    = wy + 32768;
    ushort_t* hb_hi = wb + 196608;
    ushort_t* hb_lo = hb_hi + (size_t)E_NUM * DIM;
    float*    agg   = (float*)(hb_lo + (size_t)E_NUM * DIM);
    float*    Y2    = agg + (size_t)E_NUM * DIM;

    const size_t agg_bytes = (size_t)E_NUM * DIM * sizeof(float);

    // ---- one-time prep ----
    hipMemsetAsync(counts, 0, E_NUM * sizeof(int), stream);
    hipMemsetAsync(cursor, 0, E_NUM * sizeof(int), stream);
    hist_kernel<<<P_NUM / 256, 256, 0, stream>>>(second, counts);
    scanA_kernel<<<98, 1024, 0, stream>>>(counts, offsets, bsum);
    scanB_kernel<<<1, 1, 0, stream>>>(bsum, offsets);
    scanC_kernel<<<98, 1024, 0, stream>>>(offsets, bsum);
    fill_kernel<<<P_NUM / 256, 256, 0, stream>>>(first, second, offsets, cursor,
                                                 sfirst, ssecond);
    wsplit_build_kernel<<<32, 256, 0, stream>>>(Wmsg, wt, wy);
    wb_build_kernel<<<96, 256, 0, stream>>>(gK, gU, wb);
    cast_h_kernel<<<(E_NUM * DIM) / 256, 256, 0, stream>>>(link_state, hb_hi, hb_lo);

    // ---- message-passing steps ----
    for (int t = 0; t < T_STEPS; t++) {
        y2_kernel<<<E_NUM / 32, 256, 0, stream>>>(hb_hi, hb_lo, wy, Y2);
        hipMemsetAsync(agg, 0, agg_bytes, stream);
        msg_kernel<<<P_NUM / 128, 256, 0, stream>>>(hb_hi, hb_lo, sfirst, ssecond,
                                                    wt, Y2, bmsg, agg);
        gru_kernel<<<(E_NUM + 63) / 64, 512, 0, stream>>>(agg, hb_hi, hb_lo,
                                                          wb, gbias);
    }

    // ---- pool + readout ----
    float* pooled = agg;  // reuse
    hipMemsetAsync(pooled, 0, (size_t)G_NUM * DIM * sizeof(float), stream);
    pool_kernel<<<(E_NUM * DIM) / 256, 256, 0, stream>>>(hb_hi, hb_lo, gids, pooled);
    readout_kernel<<<G_NUM, 256, 0, stream>>>(pooled, W1, b1, W2, b2, W3, b3, out);
}